// Round 9
// baseline (120.542 us; speedup 1.0000x reference)
//
#include <hip/hip_runtime.h>
#include <hip/hip_bf16.h>
#include <cmath>

// Problem constants (fixed by the reference setup)
constexpr int B = 2, S = 4096, D = 256, H = 8, K = 32;
constexpr int HK = H * K;              // 256
constexpr float LN_EPS = 1e-3f;

constexpr int QT  = 64;                // queries per attention block
constexpr int WIN = 192;               // window union = QT + 2*w2 (w2=64)
constexpr int VSTRIDE = 4224;          // padded v^T row: 64 | 4096 | 64

typedef short bf16x8 __attribute__((ext_vector_type(8)));   // 8 bf16 = 4 VGPRs
typedef float f32x4  __attribute__((ext_vector_type(4)));

static __device__ inline short f2bf(float f) {              // RNE fp32->bf16
    unsigned u = __float_as_uint(f);
    unsigned r = (u + 0x7fffu + ((u >> 16) & 1u)) >> 16;
    return (short)r;
}

// XOR-swizzled LDS fragment layout: 16-B unit (row, q) holds 8 bf16 of k-range
// q*8..q*8+7 for that row.  Swizzle gives 2-way (free) banks on frag reads.
static __device__ inline int frag_off(int row, int q) {
    return ((row << 2) + (q ^ ((row >> 1) & 3))) << 4;      // byte offset
}

// ---------------------------------------------------------------------------
// Kernel 0: convert+transpose weights to bf16 + zero v^T border (32 blocks).
// x is no longer pre-converted: qkv stages fp32 x directly.
// ---------------------------------------------------------------------------
__global__ __launch_bounds__(256) void wcvt_kernel(
    const float* __restrict__ Wq, const float* __restrict__ Wk,
    const float* __restrict__ Wv, const float* __restrict__ Wo,
    short* __restrict__ wqt, short* __restrict__ wkt,
    short* __restrict__ wvt, short* __restrict__ wot,
    short* __restrict__ vtb)
{
    const int t = threadIdx.x;
    const int mat = blockIdx.x >> 3, strip = blockIdx.x & 7;
    const int d0 = strip * 32;
    const float* src = (mat == 0) ? Wq : (mat == 1) ? Wk : (mat == 2) ? Wv : Wo;
    short* dst = (mat == 0) ? wqt : (mat == 1) ? wkt : (mat == 2) ? wvt : wot;

    __shared__ float lds[32][257];
    {   // stage 32 d-rows x 256 cols, coalesced
        const int row = t >> 3, c0 = (t & 7) * 32;
#pragma unroll
        for (int i = 0; i < 8; ++i) {
            const float4 f = *(const float4*)(src + (size_t)(d0 + row) * 256 + c0 + i * 4);
            lds[row][c0 + i * 4 + 0] = f.x; lds[row][c0 + i * 4 + 1] = f.y;
            lds[row][c0 + i * 4 + 2] = f.z; lds[row][c0 + i * 4 + 3] = f.w;
        }
    }
    __syncthreads();
    short* orow = dst + (size_t)t * 256 + d0;
#pragma unroll
    for (int u = 0; u < 4; ++u) {
        bf16x8 v;
#pragma unroll
        for (int j = 0; j < 8; ++j)
            v[j] = f2bf(lds[u * 8 + j][t]);
        *(bf16x8*)(orow + u * 8) = v;
    }

    // zero v^T border columns: 512 rows x 128 border cols, 8 elems/thread
    {
        const int e0 = (blockIdx.x * 256 + t) * 8;       // covers 65536 exactly
        const int r = e0 >> 7;                           // bh*32 + d
        const int c = e0 & 127;
        const int col = (c < 64) ? c : (VSTRIDE - 128 + c);
        short* p = vtb + (size_t)r * VSTRIDE + col;
#pragma unroll
        for (int j = 0; j < 8; ++j) p[j] = 0;
    }
}

// ---------------------------------------------------------------------------
// Kernel 1: QKV projection via MFMA, LDS-staged, high occupancy.
// Block tile 32(M) x 128(N), 4 waves (2x2) of 16x64.  BK=64 (two 32-k
// sub-tiles), next-iter register prefetch.  A staged from fp32 x with
// in-staging conversion.  LDS 20 KB.  Grid 1536 (~5-6 blocks/CU).
// ---------------------------------------------------------------------------
__global__ __launch_bounds__(256) void qkv_gemm_kernel(
    const float* __restrict__ x,
    const short* __restrict__ wqt, const short* __restrict__ wkt,
    const short* __restrict__ wvt,
    const float* __restrict__ bq, const float* __restrict__ bk,
    const float* __restrict__ bv,
    short* __restrict__ qb, short* __restrict__ kb, short* __restrict__ vtb)
{
    const int nt = blockIdx.x % 6, mt = blockIdx.x / 6;
    const int mat = nt >> 1, n0 = (nt & 1) * 128, m0 = mt * 32;
    const short* wt  = (mat == 0) ? wqt : (mat == 1) ? wkt : wvt;
    const float* bia = (mat == 0) ? bq  : (mat == 1) ? bk  : bv;

    __shared__ alignas(16) char lds[20480];     // As 4KB (2 sub-tiles) | Bs 16KB
    char* AsB = lds;
    char* BsB = lds + 4096;

    const int t = threadIdx.x, wave = t >> 6, lane = t & 63;
    const int quad = lane >> 4, l16 = lane & 15;
    const int wm = (wave & 1) * 16, wn = (wave >> 1) * 64;

    // staging: A = 256 units of 16B (1/thread, fp32->bf16), B = 1024 (4/thread)
    const int arow = t >> 3, auk = t & 7;
    int brow[4], buk[4];
#pragma unroll
    for (int i = 0; i < 4; ++i) {
        const int idx = t * 4 + i;
        brow[i] = idx >> 3; buk[i] = idx & 7;
    }

    const float* xrow = x + (size_t)(m0 + arow) * 256 + auk * 8;

    f32x4 acc[4];
#pragma unroll
    for (int j = 0; j < 4; ++j) acc[j] = (f32x4){0.f, 0.f, 0.f, 0.f};

    float4 ax0, ax1;
    bf16x8 bn[4];
    ax0 = *(const float4*)(xrow);               // preload kk=0
    ax1 = *(const float4*)(xrow + 4);
#pragma unroll
    for (int i = 0; i < 4; ++i)
        bn[i] = *(const bf16x8*)(wt + (size_t)(n0 + brow[i]) * 256 + buk[i] * 8);

    for (int kk = 0; kk < 4; ++kk) {
        __syncthreads();                        // prev compute done reading LDS
        {
            bf16x8 av;
            av[0] = f2bf(ax0.x); av[1] = f2bf(ax0.y); av[2] = f2bf(ax0.z); av[3] = f2bf(ax0.w);
            av[4] = f2bf(ax1.x); av[5] = f2bf(ax1.y); av[6] = f2bf(ax1.z); av[7] = f2bf(ax1.w);
            *(bf16x8*)(AsB + (auk >> 2) * 2048 + frag_off(arow, auk & 3)) = av;
        }
#pragma unroll
        for (int i = 0; i < 4; ++i)
            *(bf16x8*)(BsB + (buk[i] >> 2) * 8192 + frag_off(brow[i], buk[i] & 3)) = bn[i];
        __syncthreads();
        if (kk < 3) {                           // prefetch next iter
            const int kc = (kk + 1) * 64;
            ax0 = *(const float4*)(xrow + kc);
            ax1 = *(const float4*)(xrow + kc + 4);
#pragma unroll
            for (int i = 0; i < 4; ++i)
                bn[i] = *(const bf16x8*)(wt + (size_t)(n0 + brow[i]) * 256 + kc + buk[i] * 8);
        }
#pragma unroll
        for (int hh = 0; hh < 2; ++hh) {
            const bf16x8 af = *(const bf16x8*)(AsB + hh * 2048 + frag_off(wm + l16, quad));
            bf16x8 bf[4];
#pragma unroll
            for (int ni = 0; ni < 4; ++ni)
                bf[ni] = *(const bf16x8*)(BsB + hh * 8192 + frag_off(wn + ni * 16 + l16, quad));
#pragma unroll
            for (int ni = 0; ni < 4; ++ni)
                acc[ni] = __builtin_amdgcn_mfma_f32_16x16x32_bf16(af, bf[ni], acc[ni], 0, 0, 0);
        }
    }

    if (mat < 2) {
        short* dst = (mat == 0) ? qb : kb;
#pragma unroll
        for (int ni = 0; ni < 4; ++ni) {
            const int gn = n0 + wn + ni * 16 + l16;
            const float bb = bia[gn];
            const int h = gn >> 5, k2 = gn & 31;
#pragma unroll
            for (int r = 0; r < 4; ++r) {
                const int gm = m0 + wm + quad * 4 + r;
                const int b = gm >> 12, s = gm & 4095;
                dst[(((size_t)(b * 8 + h)) * 4096 + s) * 32 + k2] = f2bf(acc[ni][r] + bb);
            }
        }
    } else {
        // v transposed: 4 consecutive rows (r) -> consecutive s -> short4
#pragma unroll
        for (int ni = 0; ni < 4; ++ni) {
            const int gn = n0 + wn + ni * 16 + l16;
            const float bb = bia[gn];
            const int h = gn >> 5, k2 = gn & 31;
            const int gm0 = m0 + wm + quad * 4;
            const int b = gm0 >> 12, s0 = gm0 & 4095;
            short4 pk;
            pk.x = f2bf(acc[ni][0] + bb);
            pk.y = f2bf(acc[ni][1] + bb);
            pk.z = f2bf(acc[ni][2] + bb);
            pk.w = f2bf(acc[ni][3] + bb);
            *(short4*)(vtb + ((size_t)(b * 8 + h) * 32 + k2) * VSTRIDE + 64 + s0) = pk;
        }
    }
}

// ---------------------------------------------------------------------------
// Kernel 2: banded attention via MFMA.  Q/K fragments direct from global.
// LDS: V^T (+ ones-row 32) and P.  Softmax denominator computed BY MFMA:
// l = P @ ones via a 3rd PV accumulator (col 32).  ONE barrier.
// ---------------------------------------------------------------------------
__global__ __launch_bounds__(256) void attn_kernel(
    const short* __restrict__ qb, const short* __restrict__ kb,
    const short* __restrict__ vtb, short* __restrict__ ob,
    const int* __restrict__ w2p)
{
    const int w2 = *w2p;                    // 64
    const int bh   = blockIdx.x >> 6;
    const int tile = blockIdx.x & 63;
    const int i0 = tile * QT, jlo = i0 - w2;
    const int t = threadIdx.x, wave = t >> 6, lane = t & 63;
    const int quad = lane >> 4, l16 = lane & 15;

    __shared__ alignas(16) char lds[38912];
    short* Vts = (short*)lds;                  // [33][200]  13200 B (row 32 = ones)
    short* Ps  = (short*)(lds + 13312);        // [64][200]  25600 B

    // stage V^T window: 768 units of 16B (3/thread), from padded global
#pragma unroll
    for (int it = 0; it < 3; ++it) {
        const int idx = t + it * 256;
        const int row = idx / 24, unit = idx % 24;
        *(bf16x8*)(Vts + row * 200 + unit * 8) =
            *(const bf16x8*)(vtb + ((size_t)bh * 32 + row) * VSTRIDE + (jlo + 64) + unit * 8);
    }
    if (t < 192) Vts[32 * 200 + t] = (short)0x3F80;   // ones row (bf16 1.0)

    // ---- QK^T: Q/K frags direct from global.  Wave covers cols [wave*48,+48)
    bf16x8 af[4];
#pragma unroll
    for (int mi = 0; mi < 4; ++mi)
        af[mi] = *(const bf16x8*)(qb + ((size_t)bh * 4096 + i0 + mi * 16 + l16) * 32 + quad * 8);

    f32x4 sc[4][3];
#pragma unroll
    for (int mi = 0; mi < 4; ++mi)
#pragma unroll
        for (int ni = 0; ni < 3; ++ni) sc[mi][ni] = (f32x4){0.f, 0.f, 0.f, 0.f};
#pragma unroll
    for (int ni = 0; ni < 3; ++ni) {
        const int krow = wave * 48 + ni * 16 + l16;
        const int jc = min(max(jlo + krow, 0), S - 1);
        const bf16x8 bfr = *(const bf16x8*)(kb + ((size_t)bh * 4096 + jc) * 32 + quad * 8);
#pragma unroll
        for (int mi = 0; mi < 4; ++mi)
            sc[mi][ni] = __builtin_amdgcn_mfma_f32_16x16x32_bf16(af[mi], bfr, sc[mi][ni], 0, 0, 0);
    }

    // ---- mask + scale + exp; P -> LDS (bf16, [64][200]).  No row-reduction:
    // the denominator comes out of the PV MFMA (ones row).
    const float scale = 0.17677669529663687f;   // 1/sqrt(32)
    int colv[3]; bool jok[3];
#pragma unroll
    for (int ni = 0; ni < 3; ++ni) {
        colv[ni] = wave * 48 + ni * 16 + l16;
        const int j = jlo + colv[ni];
        jok[ni] = (j >= 0) && (j < S);
    }
#pragma unroll
    for (int mi = 0; mi < 4; ++mi)
#pragma unroll
        for (int r = 0; r < 4; ++r) {
            const int row = mi * 16 + quad * 4 + r;
#pragma unroll
            for (int ni = 0; ni < 3; ++ni) {
                const int diff = colv[ni] - row;
                const bool valid = jok[ni] && (diff >= 0) && (diff <= 2 * w2);
                const float p = valid ? __expf(sc[mi][ni][r] * scale) : 0.f;
                Ps[row * 200 + colv[ni]] = f2bf(p);
            }
        }
    __syncthreads();    // Vts staged + Ps complete

    // ---- PV: this wave computes rows [wave*16, wave*16+16) x 32 dims,
    // plus the l-column (ni=2, col 32 = ones row).
    const int orow0 = wave * 16;
    f32x4 oacc[3];
#pragma unroll
    for (int ni = 0; ni < 3; ++ni) oacc[ni] = (f32x4){0.f, 0.f, 0.f, 0.f};
#pragma unroll
    for (int kk = 0; kk < 6; ++kk) {
        const bf16x8 pa = *(const bf16x8*)(Ps + (orow0 + l16) * 200 + kk * 32 + quad * 8);
#pragma unroll
        for (int ni = 0; ni < 3; ++ni) {
            // ni=2, l16>0 reads past Vts into Ps: finite bf16, results unused.
            const bf16x8 vb = *(const bf16x8*)(Vts + (ni * 16 + l16) * 200 + kk * 32 + quad * 8);
            oacc[ni] = __builtin_amdgcn_mfma_f32_16x16x32_bf16(pa, vb, oacc[ni], 0, 0, 0);
        }
    }

    // ---- epilogue: /L (L = oacc[2] col 32, lives in lane quad*16), write bf16
    const int b = bh >> 3, h = bh & 7;
#pragma unroll
    for (int r = 0; r < 4; ++r) {
        const int row = orow0 + quad * 4 + r;
        const float L = __shfl(oacc[2][r], lane & 48);
        const float Linv = 1.f / L;
        const int s = i0 + row;
#pragma unroll
        for (int ni = 0; ni < 2; ++ni) {
            const int d = ni * 16 + l16;
            ob[((size_t)b * 4096 + s) * 256 + h * 32 + d] = f2bf(oacc[ni][r] * Linv);
        }
    }
}

// ---------------------------------------------------------------------------
// Kernel 3: out-projection via MFMA + fused residual + LayerNorm, LDS-free
// GEMM (direct-global frags).  Block tile 16(M) x 256(N), wave = 16x64.
// LDS only for the ys transpose feeding LN.  Grid 512 (2/CU).
// ---------------------------------------------------------------------------
__global__ __launch_bounds__(256) void out_ln_kernel(
    const short* __restrict__ o, const short* __restrict__ wot,
    const float* __restrict__ x, const float* __restrict__ bo,
    const float* __restrict__ gamma, const float* __restrict__ beta,
    float* __restrict__ out)
{
    __shared__ float ys[16][260];   // 16640 B

    const int t = threadIdx.x, wave = t >> 6, lane = t & 63;
    const int quad = lane >> 4, l16 = lane & 15;
    const int m0 = blockIdx.x * 16;
    const int wn = wave * 64;

    const short* abase = o   + (size_t)(m0 + l16) * 256 + quad * 8;
    const short* bbase = wot + (size_t)(wn + l16) * 256 + quad * 8;

    f32x4 acc[4];
#pragma unroll
    for (int j = 0; j < 4; ++j) acc[j] = (f32x4){0.f, 0.f, 0.f, 0.f};

#pragma unroll 2
    for (int k0 = 0; k0 < 256; k0 += 32) {
        const bf16x8 af = *(const bf16x8*)(abase + k0);
        bf16x8 bf[4];
#pragma unroll
        for (int ni = 0; ni < 4; ++ni)
            bf[ni] = *(const bf16x8*)(bbase + (size_t)ni * 16 * 256 + k0);
#pragma unroll
        for (int ni = 0; ni < 4; ++ni)
            acc[ni] = __builtin_amdgcn_mfma_f32_16x16x32_bf16(af, bf[ni], acc[ni], 0, 0, 0);
    }

#pragma unroll
    for (int ni = 0; ni < 4; ++ni) {
        const float bov = bo[wn + ni * 16 + l16];
#pragma unroll
        for (int r = 0; r < 4; ++r)
            ys[quad * 4 + r][wn + ni * 16 + l16] = acc[ni][r] + bov;
    }
    __syncthreads();

    // residual + LN: wave handles rows wave*4 .. wave*4+3
    const float4 g4 = *(const float4*)(gamma + lane * 4);
    const float4 b4 = *(const float4*)(beta + lane * 4);
#pragma unroll
    for (int rr = 0; rr < 4; ++rr) {
        const int row = wave * 4 + rr;
        const float4 av = *(const float4*)(&ys[row][lane * 4]);
        const float4 xv = *(const float4*)(x + (size_t)(m0 + row) * 256 + lane * 4);
        const float y0 = xv.x + av.x, y1 = xv.y + av.y, y2 = xv.z + av.z, y3 = xv.w + av.w;
        float sum = y0 + y1 + y2 + y3;
        float s2 = y0 * y0 + y1 * y1 + y2 * y2 + y3 * y3;
#pragma unroll
        for (int off = 32; off > 0; off >>= 1) {
            sum += __shfl_xor(sum, off);
            s2 += __shfl_xor(s2, off);
        }
        const float mu = sum * (1.f / 256.f);
        const float rstd = rsqrtf(s2 * (1.f / 256.f) - mu * mu + LN_EPS);
        float4 ov;
        ov.x = (y0 - mu) * rstd * g4.x + b4.x;
        ov.y = (y1 - mu) * rstd * g4.y + b4.y;
        ov.z = (y2 - mu) * rstd * g4.z + b4.z;
        ov.w = (y3 - mu) * rstd * g4.w + b4.w;
        *(float4*)(out + (size_t)(m0 + row) * 256 + lane * 4) = ov;
    }
}

// ---------------------------------------------------------------------------
extern "C" void kernel_launch(void* const* d_in, const int* in_sizes, int n_in,
                              void* d_out, int out_size, void* d_ws, size_t ws_size,
                              hipStream_t stream) {
    const float* x     = (const float*)d_in[0];
    const float* Wq    = (const float*)d_in[1];
    const float* bq    = (const float*)d_in[2];
    const float* Wk    = (const float*)d_in[3];
    const float* bk    = (const float*)d_in[4];
    const float* Wv    = (const float*)d_in[5];
    const float* bv    = (const float*)d_in[6];
    const float* Wo    = (const float*)d_in[7];
    const float* bo    = (const float*)d_in[8];
    const float* gamma = (const float*)d_in[9];
    const float* beta  = (const float*)d_in[10];
    const int*   w2p   = (const int*)d_in[11];
    float* out = (float*)d_out;

    const size_t NQ = (size_t)B * H * S * K;       // 2,097,152
    short* qb  = (short*)d_ws;
    short* kb  = qb + NQ;
    short* vtb = kb + NQ;                          // 16*32*VSTRIDE = 2,162,688
    short* ob  = vtb + (size_t)16 * 32 * VSTRIDE;
    short* wqt = ob + NQ;
    short* wkt = wqt + 65536;
    short* wvt = wkt + 65536;
    short* wot = wvt + 65536;

    wcvt_kernel<<<dim3(32), dim3(256), 0, stream>>>(
        Wq, Wk, Wv, Wo, wqt, wkt, wvt, wot, vtb);

    qkv_gemm_kernel<<<dim3(1536), dim3(256), 0, stream>>>(
        x, wqt, wkt, wvt, bq, bk, bv, qb, kb, vtb);

    attn_kernel<<<dim3(B * H * S / QT), dim3(256), 0, stream>>>(
        qb, kb, vtb, ob, w2p);

    out_ln_kernel<<<dim3(B * S / 16), dim3(256), 0, stream>>>(
        ob, wot, x, bo, gamma, beta, out);
}

// Round 10
// 119.188 us; speedup vs baseline: 1.0114x; 1.0114x over previous
//
#include <hip/hip_runtime.h>
#include <hip/hip_bf16.h>
#include <cmath>

// Problem constants (fixed by the reference setup)
constexpr int B = 2, S = 4096, D = 256, H = 8, K = 32;
constexpr int HK = H * K;              // 256
constexpr float LN_EPS = 1e-3f;

constexpr int QT  = 64;                // queries per attention block
constexpr int WIN = 192;               // window union = QT + 2*w2 (w2=64)
constexpr int VSTRIDE = 4224;          // padded v^T row: 64 | 4096 | 64

typedef short bf16x8 __attribute__((ext_vector_type(8)));   // 8 bf16 = 4 VGPRs
typedef float f32x4  __attribute__((ext_vector_type(4)));

static __device__ inline short f2bf(float f) {              // RNE fp32->bf16
    unsigned u = __float_as_uint(f);
    unsigned r = (u + 0x7fffu + ((u >> 16) & 1u)) >> 16;
    return (short)r;
}

// XOR-swizzled LDS fragment layout: 16-B unit (row, q) holds 8 bf16 of k-range
// q*8..q*8+7 for that row.  Swizzle gives 2-way (free) banks on frag reads.
static __device__ inline int frag_off(int row, int q) {
    return ((row << 2) + (q ^ ((row >> 1) & 3))) << 4;      // byte offset
}

// ---------------------------------------------------------------------------
// Kernel 0: convert+transpose weights to bf16 + zero v^T border (32 blocks).
// ---------------------------------------------------------------------------
__global__ __launch_bounds__(256) void wcvt_kernel(
    const float* __restrict__ Wq, const float* __restrict__ Wk,
    const float* __restrict__ Wv, const float* __restrict__ Wo,
    short* __restrict__ wqt, short* __restrict__ wkt,
    short* __restrict__ wvt, short* __restrict__ wot,
    short* __restrict__ vtb)
{
    const int t = threadIdx.x;
    const int mat = blockIdx.x >> 3, strip = blockIdx.x & 7;
    const int d0 = strip * 32;
    const float* src = (mat == 0) ? Wq : (mat == 1) ? Wk : (mat == 2) ? Wv : Wo;
    short* dst = (mat == 0) ? wqt : (mat == 1) ? wkt : (mat == 2) ? wvt : wot;

    __shared__ float lds[32][257];
    {   // stage 32 d-rows x 256 cols, coalesced
        const int row = t >> 3, c0 = (t & 7) * 32;
#pragma unroll
        for (int i = 0; i < 8; ++i) {
            const float4 f = *(const float4*)(src + (size_t)(d0 + row) * 256 + c0 + i * 4);
            lds[row][c0 + i * 4 + 0] = f.x; lds[row][c0 + i * 4 + 1] = f.y;
            lds[row][c0 + i * 4 + 2] = f.z; lds[row][c0 + i * 4 + 3] = f.w;
        }
    }
    __syncthreads();
    short* orow = dst + (size_t)t * 256 + d0;
#pragma unroll
    for (int u = 0; u < 4; ++u) {
        bf16x8 v;
#pragma unroll
        for (int j = 0; j < 8; ++j)
            v[j] = f2bf(lds[u * 8 + j][t]);
        *(bf16x8*)(orow + u * 8) = v;
    }

    // zero v^T border columns: 512 rows x 128 border cols, 8 elems/thread
    {
        const int e0 = (blockIdx.x * 256 + t) * 8;       // covers 65536 exactly
        const int r = e0 >> 7;                           // bh*32 + d
        const int c = e0 & 127;
        const int col = (c < 64) ? c : (VSTRIDE - 128 + c);
        short* p = vtb + (size_t)r * VSTRIDE + col;
#pragma unroll
        for (int j = 0; j < 8; ++j) p[j] = 0;
    }
}

// ---------------------------------------------------------------------------
// Kernel 1: QKV projection via MFMA, LDS-staged (R8 geometry).
// Block tile 64(M) x 128(N), 4 waves (2x2) of 32x64.  BK=64 (two 32-k
// sub-tiles), next-iter register prefetch.  A staged from fp32 x with
// in-staging f2bf (no separate x-conversion pass).  LDS 24 KB.  Grid 768.
// ---------------------------------------------------------------------------
__global__ __launch_bounds__(256) void qkv_gemm_kernel(
    const float* __restrict__ x,
    const short* __restrict__ wqt, const short* __restrict__ wkt,
    const short* __restrict__ wvt,
    const float* __restrict__ bq, const float* __restrict__ bk,
    const float* __restrict__ bv,
    short* __restrict__ qb, short* __restrict__ kb, short* __restrict__ vtb)
{
    const int nt = blockIdx.x % 6, mt = blockIdx.x / 6;
    const int mat = nt >> 1, n0 = (nt & 1) * 128, m0 = mt * 64;
    const short* wt  = (mat == 0) ? wqt : (mat == 1) ? wkt : wvt;
    const float* bia = (mat == 0) ? bq  : (mat == 1) ? bk  : bv;

    __shared__ alignas(16) char lds[24576];     // As 8KB (2 sub-tiles) | Bs 16KB
    char* AsB = lds;
    char* BsB = lds + 8192;

    const int t = threadIdx.x, wave = t >> 6, lane = t & 63;
    const int quad = lane >> 4, l16 = lane & 15;
    const int wm = (wave & 1) * 32, wn = (wave >> 1) * 64;

    // staging assignment: A = 512 units of 16B (2/thread), B = 1024 (4/thread)
    int arow[2], auk[2], brow[4], buk[4];
#pragma unroll
    for (int i = 0; i < 2; ++i) {
        const int idx = t * 2 + i;
        arow[i] = idx >> 3; auk[i] = idx & 7;
    }
#pragma unroll
    for (int i = 0; i < 4; ++i) {
        const int idx = t * 4 + i;
        brow[i] = idx >> 3; buk[i] = idx & 7;
    }

    f32x4 acc[2][4];
#pragma unroll
    for (int i = 0; i < 2; ++i)
#pragma unroll
        for (int j = 0; j < 4; ++j) acc[i][j] = (f32x4){0.f, 0.f, 0.f, 0.f};

    float4 ax[2][2];
    bf16x8 bn[4];
#pragma unroll
    for (int i = 0; i < 2; ++i) {               // preload kk=0 (fp32 A)
        const float* p = x + (size_t)(m0 + arow[i]) * 256 + auk[i] * 8;
        ax[i][0] = *(const float4*)(p);
        ax[i][1] = *(const float4*)(p + 4);
    }
#pragma unroll
    for (int i = 0; i < 4; ++i)
        bn[i] = *(const bf16x8*)(wt + (size_t)(n0 + brow[i]) * 256 + buk[i] * 8);

    for (int kk = 0; kk < 4; ++kk) {
        __syncthreads();                        // prev compute done reading LDS
#pragma unroll
        for (int i = 0; i < 2; ++i) {
            bf16x8 av;
            av[0] = f2bf(ax[i][0].x); av[1] = f2bf(ax[i][0].y);
            av[2] = f2bf(ax[i][0].z); av[3] = f2bf(ax[i][0].w);
            av[4] = f2bf(ax[i][1].x); av[5] = f2bf(ax[i][1].y);
            av[6] = f2bf(ax[i][1].z); av[7] = f2bf(ax[i][1].w);
            *(bf16x8*)(AsB + (auk[i] >> 2) * 4096 + frag_off(arow[i], auk[i] & 3)) = av;
        }
#pragma unroll
        for (int i = 0; i < 4; ++i)
            *(bf16x8*)(BsB + (buk[i] >> 2) * 8192 + frag_off(brow[i], buk[i] & 3)) = bn[i];
        __syncthreads();
        if (kk < 3) {                           // prefetch next iter
            const int kc = (kk + 1) * 64;
#pragma unroll
            for (int i = 0; i < 2; ++i) {
                const float* p = x + (size_t)(m0 + arow[i]) * 256 + kc + auk[i] * 8;
                ax[i][0] = *(const float4*)(p);
                ax[i][1] = *(const float4*)(p + 4);
            }
#pragma unroll
            for (int i = 0; i < 4; ++i)
                bn[i] = *(const bf16x8*)(wt + (size_t)(n0 + brow[i]) * 256 + kc + buk[i] * 8);
        }
#pragma unroll
        for (int hh = 0; hh < 2; ++hh) {
            bf16x8 af[2], bf[4];
#pragma unroll
            for (int mi = 0; mi < 2; ++mi)
                af[mi] = *(const bf16x8*)(AsB + hh * 4096 + frag_off(wm + mi * 16 + l16, quad));
#pragma unroll
            for (int ni = 0; ni < 4; ++ni)
                bf[ni] = *(const bf16x8*)(BsB + hh * 8192 + frag_off(wn + ni * 16 + l16, quad));
#pragma unroll
            for (int mi = 0; mi < 2; ++mi)
#pragma unroll
                for (int ni = 0; ni < 4; ++ni)
                    acc[mi][ni] = __builtin_amdgcn_mfma_f32_16x16x32_bf16(
                        af[mi], bf[ni], acc[mi][ni], 0, 0, 0);
        }
    }

    if (mat < 2) {
        short* dst = (mat == 0) ? qb : kb;
#pragma unroll
        for (int ni = 0; ni < 4; ++ni) {
            const int gn = n0 + wn + ni * 16 + l16;
            const float bb = bia[gn];
            const int h = gn >> 5, k2 = gn & 31;
#pragma unroll
            for (int mi = 0; mi < 2; ++mi)
#pragma unroll
                for (int r = 0; r < 4; ++r) {
                    const int gm = m0 + wm + mi * 16 + quad * 4 + r;
                    const int b = gm >> 12, s = gm & 4095;
                    dst[(((size_t)(b * 8 + h)) * 4096 + s) * 32 + k2] = f2bf(acc[mi][ni][r] + bb);
                }
        }
    } else {
        // v transposed: 4 consecutive rows (r) -> consecutive s -> short4
#pragma unroll
        for (int ni = 0; ni < 4; ++ni) {
            const int gn = n0 + wn + ni * 16 + l16;
            const float bb = bia[gn];
            const int h = gn >> 5, k2 = gn & 31;
#pragma unroll
            for (int mi = 0; mi < 2; ++mi) {
                const int gm0 = m0 + wm + mi * 16 + quad * 4;
                const int b = gm0 >> 12, s0 = gm0 & 4095;
                short4 pk;
                pk.x = f2bf(acc[mi][ni][0] + bb);
                pk.y = f2bf(acc[mi][ni][1] + bb);
                pk.z = f2bf(acc[mi][ni][2] + bb);
                pk.w = f2bf(acc[mi][ni][3] + bb);
                *(short4*)(vtb + ((size_t)(b * 8 + h) * 32 + k2) * VSTRIDE + 64 + s0) = pk;
            }
        }
    }
}

// ---------------------------------------------------------------------------
// Kernel 2: banded attention via MFMA.  Q/K fragments direct from global.
// LDS: V^T (+ ones-row 32) and P.  Softmax denominator computed BY MFMA:
// l = P @ ones via a 3rd PV accumulator (col 32).  ONE barrier.
// ---------------------------------------------------------------------------
__global__ __launch_bounds__(256) void attn_kernel(
    const short* __restrict__ qb, const short* __restrict__ kb,
    const short* __restrict__ vtb, short* __restrict__ ob,
    const int* __restrict__ w2p)
{
    const int w2 = *w2p;                    // 64
    const int bh   = blockIdx.x >> 6;
    const int tile = blockIdx.x & 63;
    const int i0 = tile * QT, jlo = i0 - w2;
    const int t = threadIdx.x, wave = t >> 6, lane = t & 63;
    const int quad = lane >> 4, l16 = lane & 15;

    __shared__ alignas(16) char lds[38912];
    short* Vts = (short*)lds;                  // [33][200]  13200 B (row 32 = ones)
    short* Ps  = (short*)(lds + 13312);        // [64][200]  25600 B

    // stage V^T window: 768 units of 16B (3/thread), from padded global
#pragma unroll
    for (int it = 0; it < 3; ++it) {
        const int idx = t + it * 256;
        const int row = idx / 24, unit = idx % 24;
        *(bf16x8*)(Vts + row * 200 + unit * 8) =
            *(const bf16x8*)(vtb + ((size_t)bh * 32 + row) * VSTRIDE + (jlo + 64) + unit * 8);
    }
    if (t < 192) Vts[32 * 200 + t] = (short)0x3F80;   // ones row (bf16 1.0)

    // ---- QK^T: Q/K frags direct from global.  Wave covers cols [wave*48,+48)
    bf16x8 af[4];
#pragma unroll
    for (int mi = 0; mi < 4; ++mi)
        af[mi] = *(const bf16x8*)(qb + ((size_t)bh * 4096 + i0 + mi * 16 + l16) * 32 + quad * 8);

    f32x4 sc[4][3];
#pragma unroll
    for (int mi = 0; mi < 4; ++mi)
#pragma unroll
        for (int ni = 0; ni < 3; ++ni) sc[mi][ni] = (f32x4){0.f, 0.f, 0.f, 0.f};
#pragma unroll
    for (int ni = 0; ni < 3; ++ni) {
        const int krow = wave * 48 + ni * 16 + l16;
        const int jc = min(max(jlo + krow, 0), S - 1);
        const bf16x8 bfr = *(const bf16x8*)(kb + ((size_t)bh * 4096 + jc) * 32 + quad * 8);
#pragma unroll
        for (int mi = 0; mi < 4; ++mi)
            sc[mi][ni] = __builtin_amdgcn_mfma_f32_16x16x32_bf16(af[mi], bfr, sc[mi][ni], 0, 0, 0);
    }

    // ---- mask + scale + exp; P -> LDS (bf16, [64][200]).  No row-reduction:
    // the denominator comes out of the PV MFMA (ones row).
    const float scale = 0.17677669529663687f;   // 1/sqrt(32)
    int colv[3]; bool jok[3];
#pragma unroll
    for (int ni = 0; ni < 3; ++ni) {
        colv[ni] = wave * 48 + ni * 16 + l16;
        const int j = jlo + colv[ni];
        jok[ni] = (j >= 0) && (j < S);
    }
#pragma unroll
    for (int mi = 0; mi < 4; ++mi)
#pragma unroll
        for (int r = 0; r < 4; ++r) {
            const int row = mi * 16 + quad * 4 + r;
#pragma unroll
            for (int ni = 0; ni < 3; ++ni) {
                const int diff = colv[ni] - row;
                const bool valid = jok[ni] && (diff >= 0) && (diff <= 2 * w2);
                const float p = valid ? __expf(sc[mi][ni][r] * scale) : 0.f;
                Ps[row * 200 + colv[ni]] = f2bf(p);
            }
        }
    __syncthreads();    // Vts staged + Ps complete

    // ---- PV: this wave computes rows [wave*16, wave*16+16) x 32 dims,
    // plus the l-column (ni=2, col 32 = ones row).
    const int orow0 = wave * 16;
    f32x4 oacc[3];
#pragma unroll
    for (int ni = 0; ni < 3; ++ni) oacc[ni] = (f32x4){0.f, 0.f, 0.f, 0.f};
#pragma unroll
    for (int kk = 0; kk < 6; ++kk) {
        const bf16x8 pa = *(const bf16x8*)(Ps + (orow0 + l16) * 200 + kk * 32 + quad * 8);
#pragma unroll
        for (int ni = 0; ni < 3; ++ni) {
            // ni=2, l16>0 reads past Vts into Ps: finite bf16, results unused.
            const bf16x8 vb = *(const bf16x8*)(Vts + (ni * 16 + l16) * 200 + kk * 32 + quad * 8);
            oacc[ni] = __builtin_amdgcn_mfma_f32_16x16x32_bf16(pa, vb, oacc[ni], 0, 0, 0);
        }
    }

    // ---- epilogue: /L (L = oacc[2] col 32, lives in lane quad*16), write bf16
    const int b = bh >> 3, h = bh & 7;
#pragma unroll
    for (int r = 0; r < 4; ++r) {
        const int row = orow0 + quad * 4 + r;
        const float L = __shfl(oacc[2][r], lane & 48);
        const float Linv = 1.f / L;
        const int s = i0 + row;
#pragma unroll
        for (int ni = 0; ni < 2; ++ni) {
            const int d = ni * 16 + l16;
            ob[((size_t)b * 4096 + s) * 256 + h * 32 + d] = f2bf(oacc[ni][r] * Linv);
        }
    }
}

// ---------------------------------------------------------------------------
// Kernel 3: out-projection via MFMA + fused residual + LayerNorm, LDS-free
// GEMM (direct-global frags).  Block tile 16(M) x 256(N), wave = 16x64.
// LDS only for the ys transpose feeding LN.  Grid 512 (2/CU).
// ---------------------------------------------------------------------------
__global__ __launch_bounds__(256) void out_ln_kernel(
    const short* __restrict__ o, const short* __restrict__ wot,
    const float* __restrict__ x, const float* __restrict__ bo,
    const float* __restrict__ gamma, const float* __restrict__ beta,
    float* __restrict__ out)
{
    __shared__ float ys[16][260];   // 16640 B

    const int t = threadIdx.x, wave = t >> 6, lane = t & 63;
    const int quad = lane >> 4, l16 = lane & 15;
    const int m0 = blockIdx.x * 16;
    const int wn = wave * 64;

    const short* abase = o   + (size_t)(m0 + l16) * 256 + quad * 8;
    const short* bbase = wot + (size_t)(wn + l16) * 256 + quad * 8;

    f32x4 acc[4];
#pragma unroll
    for (int j = 0; j < 4; ++j) acc[j] = (f32x4){0.f, 0.f, 0.f, 0.f};

#pragma unroll 2
    for (int k0 = 0; k0 < 256; k0 += 32) {
        const bf16x8 af = *(const bf16x8*)(abase + k0);
        bf16x8 bf[4];
#pragma unroll
        for (int ni = 0; ni < 4; ++ni)
            bf[ni] = *(const bf16x8*)(bbase + (size_t)ni * 16 * 256 + k0);
#pragma unroll
        for (int ni = 0; ni < 4; ++ni)
            acc[ni] = __builtin_amdgcn_mfma_f32_16x16x32_bf16(af, bf[ni], acc[ni], 0, 0, 0);
    }

#pragma unroll
    for (int ni = 0; ni < 4; ++ni) {
        const float bov = bo[wn + ni * 16 + l16];
#pragma unroll
        for (int r = 0; r < 4; ++r)
            ys[quad * 4 + r][wn + ni * 16 + l16] = acc[ni][r] + bov;
    }
    __syncthreads();

    // residual + LN: wave handles rows wave*4 .. wave*4+3
    const float4 g4 = *(const float4*)(gamma + lane * 4);
    const float4 b4 = *(const float4*)(beta + lane * 4);
#pragma unroll
    for (int rr = 0; rr < 4; ++rr) {
        const int row = wave * 4 + rr;
        const float4 av = *(const float4*)(&ys[row][lane * 4]);
        const float4 xv = *(const float4*)(x + (size_t)(m0 + row) * 256 + lane * 4);
        const float y0 = xv.x + av.x, y1 = xv.y + av.y, y2 = xv.z + av.z, y3 = xv.w + av.w;
        float sum = y0 + y1 + y2 + y3;
        float s2 = y0 * y0 + y1 * y1 + y2 * y2 + y3 * y3;
#pragma unroll
        for (int off = 32; off > 0; off >>= 1) {
            sum += __shfl_xor(sum, off);
            s2 += __shfl_xor(s2, off);
        }
        const float mu = sum * (1.f / 256.f);
        const float rstd = rsqrtf(s2 * (1.f / 256.f) - mu * mu + LN_EPS);
        float4 ov;
        ov.x = (y0 - mu) * rstd * g4.x + b4.x;
        ov.y = (y1 - mu) * rstd * g4.y + b4.y;
        ov.z = (y2 - mu) * rstd * g4.z + b4.z;
        ov.w = (y3 - mu) * rstd * g4.w + b4.w;
        *(float4*)(out + (size_t)(m0 + row) * 256 + lane * 4) = ov;
    }
}

// ---------------------------------------------------------------------------
extern "C" void kernel_launch(void* const* d_in, const int* in_sizes, int n_in,
                              void* d_out, int out_size, void* d_ws, size_t ws_size,
                              hipStream_t stream) {
    const float* x     = (const float*)d_in[0];
    const float* Wq    = (const float*)d_in[1];
    const float* bq    = (const float*)d_in[2];
    const float* Wk    = (const float*)d_in[3];
    const float* bk    = (const float*)d_in[4];
    const float* Wv    = (const float*)d_in[5];
    const float* bv    = (const float*)d_in[6];
    const float* Wo    = (const float*)d_in[7];
    const float* bo    = (const float*)d_in[8];
    const float* gamma = (const float*)d_in[9];
    const float* beta  = (const float*)d_in[10];
    const int*   w2p   = (const int*)d_in[11];
    float* out = (float*)d_out;

    const size_t NQ = (size_t)B * H * S * K;       // 2,097,152
    short* qb  = (short*)d_ws;
    short* kb  = qb + NQ;
    short* vtb = kb + NQ;                          // 16*32*VSTRIDE = 2,162,688
    short* ob  = vtb + (size_t)16 * 32 * VSTRIDE;
    short* wqt = ob + NQ;
    short* wkt = wqt + 65536;
    short* wvt = wkt + 65536;
    short* wot = wvt + 65536;

    wcvt_kernel<<<dim3(32), dim3(256), 0, stream>>>(
        Wq, Wk, Wv, Wo, wqt, wkt, wvt, wot, vtb);

    qkv_gemm_kernel<<<dim3(768), dim3(256), 0, stream>>>(
        x, wqt, wkt, wvt, bq, bk, bv, qb, kb, vtb);

    attn_kernel<<<dim3(B * H * S / QT), dim3(256), 0, stream>>>(
        qb, kb, vtb, ob, w2p);

    out_ln_kernel<<<dim3(B * S / 16), dim3(256), 0, stream>>>(
        ob, wot, x, bo, gamma, beta, out);
}

// Round 12
// 117.056 us; speedup vs baseline: 1.0298x; 1.0182x over previous
//
#include <hip/hip_runtime.h>
#include <hip/hip_bf16.h>
#include <cmath>

// Problem constants (fixed by the reference setup)
constexpr int B = 2, S = 4096, D = 256, H = 8, K = 32;
constexpr int HK = H * K;              // 256
constexpr float LN_EPS = 1e-3f;

constexpr int QT  = 64;                // queries per attention block
constexpr int WIN = 192;               // window union = QT + 2*w2 (w2=64)
constexpr int VSTRIDE = 4224;          // padded v^T row: 64 | 4096 | 64

typedef short bf16x8 __attribute__((ext_vector_type(8)));   // 8 bf16 = 4 VGPRs
typedef float f32x4  __attribute__((ext_vector_type(4)));

static __device__ inline short f2bf(float f) {              // RNE fp32->bf16
    unsigned u = __float_as_uint(f);
    unsigned r = (u + 0x7fffu + ((u >> 16) & 1u)) >> 16;
    return (short)r;
}

// XOR-swizzled LDS fragment layout: 16-B unit (row, q) holds 8 bf16 of k-range
// q*8..q*8+7 for that row.  Swizzle gives 2-way (free) banks on frag reads.
static __device__ inline int frag_off(int row, int q) {
    return ((row << 2) + (q ^ ((row >> 1) & 3))) << 4;      // byte offset
}

// ---------------------------------------------------------------------------
// Kernel 0: blocks 0..31: convert+transpose weights to bf16 + zero v^T border.
//           blocks 32..1055: convert x fp32 -> bf16 (8 elems/thread).
// ---------------------------------------------------------------------------
__global__ __launch_bounds__(256) void wcvt_kernel(
    const float* __restrict__ Wq, const float* __restrict__ Wk,
    const float* __restrict__ Wv, const float* __restrict__ Wo,
    const float* __restrict__ x,
    short* __restrict__ wqt, short* __restrict__ wkt,
    short* __restrict__ wvt, short* __restrict__ wot,
    short* __restrict__ vtb, short* __restrict__ xb)
{
    const int t = threadIdx.x;
    if (blockIdx.x >= 32) {
        const int i = ((blockIdx.x - 32) * 256 + t) * 8;    // < 2,097,152
        const float4 a = *(const float4*)(x + i);
        const float4 b = *(const float4*)(x + i + 4);
        bf16x8 o;
        o[0] = f2bf(a.x); o[1] = f2bf(a.y); o[2] = f2bf(a.z); o[3] = f2bf(a.w);
        o[4] = f2bf(b.x); o[5] = f2bf(b.y); o[6] = f2bf(b.z); o[7] = f2bf(b.w);
        *(bf16x8*)(xb + i) = o;
        return;
    }
    const int mat = blockIdx.x >> 3, strip = blockIdx.x & 7;
    const int d0 = strip * 32;
    const float* src = (mat == 0) ? Wq : (mat == 1) ? Wk : (mat == 2) ? Wv : Wo;
    short* dst = (mat == 0) ? wqt : (mat == 1) ? wkt : (mat == 2) ? wvt : wot;

    __shared__ float lds[32][257];
    {   // stage 32 d-rows x 256 cols, coalesced
        const int row = t >> 3, c0 = (t & 7) * 32;
#pragma unroll
        for (int i = 0; i < 8; ++i) {
            const float4 f = *(const float4*)(src + (size_t)(d0 + row) * 256 + c0 + i * 4);
            lds[row][c0 + i * 4 + 0] = f.x; lds[row][c0 + i * 4 + 1] = f.y;
            lds[row][c0 + i * 4 + 2] = f.z; lds[row][c0 + i * 4 + 3] = f.w;
        }
    }
    __syncthreads();
    short* orow = dst + (size_t)t * 256 + d0;
#pragma unroll
    for (int u = 0; u < 4; ++u) {
        bf16x8 v;
#pragma unroll
        for (int j = 0; j < 8; ++j)
            v[j] = f2bf(lds[u * 8 + j][t]);
        *(bf16x8*)(orow + u * 8) = v;
    }

    // zero v^T border columns: 512 rows x 128 border cols, 8 elems/thread
    {
        const int e0 = (blockIdx.x * 256 + t) * 8;       // < 65536
        const int r = e0 >> 7;                           // bh*32 + d
        const int c = e0 & 127;
        const int col = (c < 64) ? c : (VSTRIDE - 128 + c);
        short* p = vtb + (size_t)r * VSTRIDE + col;
#pragma unroll
        for (int j = 0; j < 8; ++j) p[j] = 0;
    }
}

// ---------------------------------------------------------------------------
// Kernel 1: QKV projection via MFMA, LDS-staged, retiled for occupancy.
// Block tile 64(M) x 128(N), 4 waves (2x2) of 32x64.  BK=64 (two 32-k
// sub-tiles), next-iter register prefetch.  LDS 24 KB -> up to 6 blocks/CU.
// Grid: 128 m-tiles x 6 (3 matrices x 2 n-halves) = 768 blocks (3/CU).
// ---------------------------------------------------------------------------
__global__ __launch_bounds__(256) void qkv_gemm_kernel(
    const short* __restrict__ xb,
    const short* __restrict__ wqt, const short* __restrict__ wkt,
    const short* __restrict__ wvt,
    const float* __restrict__ bq, const float* __restrict__ bk,
    const float* __restrict__ bv,
    short* __restrict__ qb, short* __restrict__ kb, short* __restrict__ vtb)
{
    const int nt = blockIdx.x % 6, mt = blockIdx.x / 6;
    const int mat = nt >> 1, n0 = (nt & 1) * 128, m0 = mt * 64;
    const short* wt  = (mat == 0) ? wqt : (mat == 1) ? wkt : wvt;
    const float* bia = (mat == 0) ? bq  : (mat == 1) ? bk  : bv;

    __shared__ alignas(16) char lds[24576];     // As 8KB (2 sub-tiles) | Bs 16KB
    char* AsB = lds;
    char* BsB = lds + 8192;

    const int t = threadIdx.x, wave = t >> 6, lane = t & 63;
    const int quad = lane >> 4, l16 = lane & 15;
    const int wm = (wave & 1) * 32, wn = (wave >> 1) * 64;

    // staging assignment: A = 512 units of 16B (2/thread), B = 1024 (4/thread)
    int arow[2], auk[2], brow[4], buk[4];
#pragma unroll
    for (int i = 0; i < 2; ++i) {
        const int idx = t * 2 + i;
        arow[i] = idx >> 3; auk[i] = idx & 7;
    }
#pragma unroll
    for (int i = 0; i < 4; ++i) {
        const int idx = t * 4 + i;
        brow[i] = idx >> 3; buk[i] = idx & 7;
    }

    f32x4 acc[2][4];
#pragma unroll
    for (int i = 0; i < 2; ++i)
#pragma unroll
        for (int j = 0; j < 4; ++j) acc[i][j] = (f32x4){0.f, 0.f, 0.f, 0.f};

    bf16x8 an[2], bn[4];
#pragma unroll
    for (int i = 0; i < 2; ++i)                 // preload kk=0
        an[i] = *(const bf16x8*)(xb + (size_t)(m0 + arow[i]) * 256 + auk[i] * 8);
#pragma unroll
    for (int i = 0; i < 4; ++i)
        bn[i] = *(const bf16x8*)(wt + (size_t)(n0 + brow[i]) * 256 + buk[i] * 8);

    for (int kk = 0; kk < 4; ++kk) {
        __syncthreads();                        // prev compute done reading LDS
#pragma unroll
        for (int i = 0; i < 2; ++i)
            *(bf16x8*)(AsB + (auk[i] >> 2) * 4096 + frag_off(arow[i], auk[i] & 3)) = an[i];
#pragma unroll
        for (int i = 0; i < 4; ++i)
            *(bf16x8*)(BsB + (buk[i] >> 2) * 8192 + frag_off(brow[i], buk[i] & 3)) = bn[i];
        __syncthreads();
        if (kk < 3) {                           // prefetch next iter
            const int kc = (kk + 1) * 64;
#pragma unroll
            for (int i = 0; i < 2; ++i)
                an[i] = *(const bf16x8*)(xb + (size_t)(m0 + arow[i]) * 256 + kc + auk[i] * 8);
#pragma unroll
            for (int i = 0; i < 4; ++i)
                bn[i] = *(const bf16x8*)(wt + (size_t)(n0 + brow[i]) * 256 + kc + buk[i] * 8);
        }
#pragma unroll
        for (int hh = 0; hh < 2; ++hh) {
            bf16x8 af[2], bf[4];
#pragma unroll
            for (int mi = 0; mi < 2; ++mi)
                af[mi] = *(const bf16x8*)(AsB + hh * 4096 + frag_off(wm + mi * 16 + l16, quad));
#pragma unroll
            for (int ni = 0; ni < 4; ++ni)
                bf[ni] = *(const bf16x8*)(BsB + hh * 8192 + frag_off(wn + ni * 16 + l16, quad));
#pragma unroll
            for (int mi = 0; mi < 2; ++mi)
#pragma unroll
                for (int ni = 0; ni < 4; ++ni)
                    acc[mi][ni] = __builtin_amdgcn_mfma_f32_16x16x32_bf16(
                        af[mi], bf[ni], acc[mi][ni], 0, 0, 0);
        }
    }

    if (mat < 2) {
        short* dst = (mat == 0) ? qb : kb;
#pragma unroll
        for (int ni = 0; ni < 4; ++ni) {
            const int gn = n0 + wn + ni * 16 + l16;
            const float bb = bia[gn];
            const int h = gn >> 5, k2 = gn & 31;
#pragma unroll
            for (int mi = 0; mi < 2; ++mi)
#pragma unroll
                for (int r = 0; r < 4; ++r) {
                    const int gm = m0 + wm + mi * 16 + quad * 4 + r;
                    const int b = gm >> 12, s = gm & 4095;
                    dst[(((size_t)(b * 8 + h)) * 4096 + s) * 32 + k2] = f2bf(acc[mi][ni][r] + bb);
                }
        }
    } else {
        // v transposed: 4 consecutive rows (r) -> consecutive s -> short4
#pragma unroll
        for (int ni = 0; ni < 4; ++ni) {
            const int gn = n0 + wn + ni * 16 + l16;
            const float bb = bia[gn];
            const int h = gn >> 5, k2 = gn & 31;
#pragma unroll
            for (int mi = 0; mi < 2; ++mi) {
                const int gm0 = m0 + wm + mi * 16 + quad * 4;
                const int b = gm0 >> 12, s0 = gm0 & 4095;
                short4 pk;
                pk.x = f2bf(acc[mi][ni][0] + bb);
                pk.y = f2bf(acc[mi][ni][1] + bb);
                pk.z = f2bf(acc[mi][ni][2] + bb);
                pk.w = f2bf(acc[mi][ni][3] + bb);
                *(short4*)(vtb + ((size_t)(b * 8 + h) * 32 + k2) * VSTRIDE + 64 + s0) = pk;
            }
        }
    }
}

// ---------------------------------------------------------------------------
// Kernel 2: banded attention via MFMA.  Q/K fragments direct from global.
// LDS: V^T (+ ones-row 32) and P.  Softmax denominator computed BY MFMA:
// l = P @ ones via a 3rd PV accumulator (col 32), replacing 64 shfl-reduces
// with 6 MFMAs; epilogue pulls L with one shfl.  ONE barrier.
// ---------------------------------------------------------------------------
__global__ __launch_bounds__(256) void attn_kernel(
    const short* __restrict__ qb, const short* __restrict__ kb,
    const short* __restrict__ vtb, short* __restrict__ ob,
    const int* __restrict__ w2p)
{
    const int w2 = *w2p;                    // 64
    const int bh   = blockIdx.x >> 6;
    const int tile = blockIdx.x & 63;
    const int i0 = tile * QT, jlo = i0 - w2;
    const int t = threadIdx.x, wave = t >> 6, lane = t & 63;
    const int quad = lane >> 4, l16 = lane & 15;

    __shared__ alignas(16) char lds[38912];
    short* Vts = (short*)lds;                  // [33][200]  13200 B (row 32 = ones)
    short* Ps  = (short*)(lds + 13312);        // [64][200]  25600 B

    // stage V^T window: 768 units of 16B (3/thread), from padded global
#pragma unroll
    for (int it = 0; it < 3; ++it) {
        const int idx = t + it * 256;
        const int row = idx / 24, unit = idx % 24;
        *(bf16x8*)(Vts + row * 200 + unit * 8) =
            *(const bf16x8*)(vtb + ((size_t)bh * 32 + row) * VSTRIDE + (jlo + 64) + unit * 8);
    }
    if (t < 192) Vts[32 * 200 + t] = (short)0x3F80;   // ones row (bf16 1.0)

    // ---- QK^T: Q/K frags direct from global.  Wave covers cols [wave*48,+48)
    bf16x8 af[4];
#pragma unroll
    for (int mi = 0; mi < 4; ++mi)
        af[mi] = *(const bf16x8*)(qb + ((size_t)bh * 4096 + i0 + mi * 16 + l16) * 32 + quad * 8);

    f32x4 sc[4][3];
#pragma unroll
    for (int mi = 0; mi < 4; ++mi)
#pragma unroll
        for (int ni = 0; ni < 3; ++ni) sc[mi][ni] = (f32x4){0.f, 0.f, 0.f, 0.f};
#pragma unroll
    for (int ni = 0; ni < 3; ++ni) {
        const int krow = wave * 48 + ni * 16 + l16;
        const int jc = min(max(jlo + krow, 0), S - 1);
        const bf16x8 bfr = *(const bf16x8*)(kb + ((size_t)bh * 4096 + jc) * 32 + quad * 8);
#pragma unroll
        for (int mi = 0; mi < 4; ++mi)
            sc[mi][ni] = __builtin_amdgcn_mfma_f32_16x16x32_bf16(af[mi], bfr, sc[mi][ni], 0, 0, 0);
    }

    // ---- mask + scale + exp; P -> LDS (bf16, [64][200]).  No row-reduction:
    // the denominator comes out of the PV MFMA (ones row).
    const float scale = 0.17677669529663687f;   // 1/sqrt(32)
    int colv[3]; bool jok[3];
#pragma unroll
    for (int ni = 0; ni < 3; ++ni) {
        colv[ni] = wave * 48 + ni * 16 + l16;
        const int j = jlo + colv[ni];
        jok[ni] = (j >= 0) && (j < S);
    }
#pragma unroll
    for (int mi = 0; mi < 4; ++mi)
#pragma unroll
        for (int r = 0; r < 4; ++r) {
            const int row = mi * 16 + quad * 4 + r;
#pragma unroll
            for (int ni = 0; ni < 3; ++ni) {
                const int diff = colv[ni] - row;
                const bool valid = jok[ni] && (diff >= 0) && (diff <= 2 * w2);
                const float p = valid ? __expf(sc[mi][ni][r] * scale) : 0.f;
                Ps[row * 200 + colv[ni]] = f2bf(p);
            }
        }
    __syncthreads();    // Vts staged + Ps complete

    // ---- PV: this wave computes rows [wave*16, wave*16+16) x 32 dims,
    // plus the l-column (ni=2, col 32 = ones row).
    const int orow0 = wave * 16;
    f32x4 oacc[3];
#pragma unroll
    for (int ni = 0; ni < 3; ++ni) oacc[ni] = (f32x4){0.f, 0.f, 0.f, 0.f};
#pragma unroll
    for (int kk = 0; kk < 6; ++kk) {
        const bf16x8 pa = *(const bf16x8*)(Ps + (orow0 + l16) * 200 + kk * 32 + quad * 8);
#pragma unroll
        for (int ni = 0; ni < 3; ++ni) {
            // ni=2, l16>0 reads past Vts into Ps: finite bf16, results unused.
            const bf16x8 vb = *(const bf16x8*)(Vts + (ni * 16 + l16) * 200 + kk * 32 + quad * 8);
            oacc[ni] = __builtin_amdgcn_mfma_f32_16x16x32_bf16(pa, vb, oacc[ni], 0, 0, 0);
        }
    }

    // ---- epilogue: /L (L = oacc[2] col 32, lives in lane quad*16), write bf16
    const int b = bh >> 3, h = bh & 7;
#pragma unroll
    for (int r = 0; r < 4; ++r) {
        const int row = orow0 + quad * 4 + r;
        const float L = __shfl(oacc[2][r], lane & 48);
        const float Linv = 1.f / L;
        const int s = i0 + row;
#pragma unroll
        for (int ni = 0; ni < 2; ++ni) {
            const int d = ni * 16 + l16;
            ob[((size_t)b * 4096 + s) * 256 + h * 32 + d] = f2bf(oacc[ni][r] * Linv);
        }
    }
}

// ---------------------------------------------------------------------------
// Kernel 3: out-projection via MFMA + fused residual + LayerNorm, LDS-free
// GEMM (direct-global frags).  Block tile 16(M) x 256(N), wave = 16x64.
// LDS only for the ys transpose feeding LN.  Grid 512 (2/CU).
// ---------------------------------------------------------------------------
__global__ __launch_bounds__(256) void out_ln_kernel(
    const short* __restrict__ o, const short* __restrict__ wot,
    const float* __restrict__ x, const float* __restrict__ bo,
    const float* __restrict__ gamma, const float* __restrict__ beta,
    float* __restrict__ out)
{
    __shared__ float ys[16][260];   // 16640 B

    const int t = threadIdx.x, wave = t >> 6, lane = t & 63;
    const int quad = lane >> 4, l16 = lane & 15;
    const int m0 = blockIdx.x * 16;
    const int wn = wave * 64;

    const short* abase = o   + (size_t)(m0 + l16) * 256 + quad * 8;
    const short* bbase = wot + (size_t)(wn + l16) * 256 + quad * 8;

    f32x4 acc[4];
#pragma unroll
    for (int j = 0; j < 4; ++j) acc[j] = (f32x4){0.f, 0.f, 0.f, 0.f};

#pragma unroll 2
    for (int k0 = 0; k0 < 256; k0 += 32) {
        const bf16x8 af = *(const bf16x8*)(abase + k0);
        bf16x8 bf[4];
#pragma unroll
        for (int ni = 0; ni < 4; ++ni)
            bf[ni] = *(const bf16x8*)(bbase + (size_t)ni * 16 * 256 + k0);
#pragma unroll
        for (int ni = 0; ni < 4; ++ni)
            acc[ni] = __builtin_amdgcn_mfma_f32_16x16x32_bf16(af, bf[ni], acc[ni], 0, 0, 0);
    }

#pragma unroll
    for (int ni = 0; ni < 4; ++ni) {
        const float bov = bo[wn + ni * 16 + l16];
#pragma unroll
        for (int r = 0; r < 4; ++r)
            ys[quad * 4 + r][wn + ni * 16 + l16] = acc[ni][r] + bov;
    }
    __syncthreads();

    // residual + LN: wave handles rows wave*4 .. wave*4+3
    const float4 g4 = *(const float4*)(gamma + lane * 4);
    const float4 b4 = *(const float4*)(beta + lane * 4);
#pragma unroll
    for (int rr = 0; rr < 4; ++rr) {
        const int row = wave * 4 + rr;
        const float4 av = *(const float4*)(&ys[row][lane * 4]);
        const float4 xv = *(const float4*)(x + (size_t)(m0 + row) * 256 + lane * 4);
        const float y0 = xv.x + av.x, y1 = xv.y + av.y, y2 = xv.z + av.z, y3 = xv.w + av.w;
        float sum = y0 + y1 + y2 + y3;
        float s2 = y0 * y0 + y1 * y1 + y2 * y2 + y3 * y3;
#pragma unroll
        for (int off = 32; off > 0; off >>= 1) {
            sum += __shfl_xor(sum, off);
            s2 += __shfl_xor(s2, off);
        }
        const float mu = sum * (1.f / 256.f);
        const float rstd = rsqrtf(s2 * (1.f / 256.f) - mu * mu + LN_EPS);
        float4 ov;
        ov.x = (y0 - mu) * rstd * g4.x + b4.x;
        ov.y = (y1 - mu) * rstd * g4.y + b4.y;
        ov.z = (y2 - mu) * rstd * g4.z + b4.z;
        ov.w = (y3 - mu) * rstd * g4.w + b4.w;
        *(float4*)(out + (size_t)(m0 + row) * 256 + lane * 4) = ov;
    }
}

// ---------------------------------------------------------------------------
extern "C" void kernel_launch(void* const* d_in, const int* in_sizes, int n_in,
                              void* d_out, int out_size, void* d_ws, size_t ws_size,
                              hipStream_t stream) {
    const float* x     = (const float*)d_in[0];
    const float* Wq    = (const float*)d_in[1];
    const float* bq    = (const float*)d_in[2];
    const float* Wk    = (const float*)d_in[3];
    const float* bk    = (const float*)d_in[4];
    const float* Wv    = (const float*)d_in[5];
    const float* bv    = (const float*)d_in[6];
    const float* Wo    = (const float*)d_in[7];
    const float* bo    = (const float*)d_in[8];
    const float* gamma = (const float*)d_in[9];
    const float* beta  = (const float*)d_in[10];
    const int*   w2p   = (const int*)d_in[11];
    float* out = (float*)d_out;

    const size_t NQ = (size_t)B * H * S * K;       // 2,097,152
    short* qb  = (short*)d_ws;
    short* kb  = qb + NQ;
    short* vtb = kb + NQ;                          // 16*32*VSTRIDE = 2,162,688
    short* ob  = vtb + (size_t)16 * 32 * VSTRIDE;
    short* wqt = ob + NQ;
    short* wkt = wqt + 65536;
    short* wvt = wkt + 65536;
    short* wot = wvt + 65536;
    short* xb  = wot + 65536;                      // 2,097,152 bf16

    wcvt_kernel<<<dim3(32 + 1024), dim3(256), 0, stream>>>(
        Wq, Wk, Wv, Wo, x, wqt, wkt, wvt, wot, vtb, xb);

    qkv_gemm_kernel<<<dim3(768), dim3(256), 0, stream>>>(
        xb, wqt, wkt, wvt, bq, bk, bv, qb, kb, vtb);

    attn_kernel<<<dim3(B * H * S / QT), dim3(256), 0, stream>>>(
        qb, kb, vtb, ob, w2p);

    out_ln_kernel<<<dim3(B * S / 16), dim3(256), 0, stream>>>(
        ob, wot, x, bo, gamma, beta, out);
}